// Round 5
// baseline (3221.558 us; speedup 1.0000x reference)
//
#include <hip/hip_runtime.h>
#include <hip/hip_bf16.h>

// ============================================================================
// PseudoLabelGenerator: round 5 — LSTM spill elimination:
//   layer-1 weights in LDS (80 KB), layer-2 weights in regs (64 VGPR),
//   total reg demand ~222 < 256 cap -> zero scratch traffic.
//   exp2-based activations (fewer VALU ops, branchless saturation).
//  K1 pack / K2 probs / K3 conf / K5-K7 CSR build / K8 gather: unchanged.
// ============================================================================

#define HIDN 256
#define NC 10
#define TSTEPS 12
#define NHEADS 4
#define LH 128

typedef __attribute__((ext_vector_type(8))) short short8;
typedef __attribute__((ext_vector_type(4))) float floatx4;

__device__ __forceinline__ unsigned short f2bf(float x) {
  unsigned u = __float_as_uint(x);
  u = u + 0x7FFFu + ((u >> 16) & 1u);   // round-to-nearest-even
  return (unsigned short)(u >> 16);
}
__device__ __forceinline__ unsigned char f2fp8(float x) {
  return (unsigned char)(__builtin_amdgcn_cvt_pk_fp8_f32(x, 0.f, 0, false) & 0xff);
}
__device__ __forceinline__ float sigf(float x) { return 1.0f / (1.0f + __expf(-x)); }
__device__ __forceinline__ float tanhf_fast(float x) {
  x = fminf(fmaxf(x, -15.f), 15.f);
  float e = __expf(-2.f * x);
  return (1.f - e) / (1.f + e);
}
// exp2-based: mul+exp+add+rcp (sig), mul+exp+add+rcp+fma (tanh); saturate at +-inf
#define LOG2E 1.44269504f
__device__ __forceinline__ float sig2(float x) {
  return 1.f / (1.f + exp2f(-LOG2E * x));
}
__device__ __forceinline__ float tanh2(float x) {
  return 1.f - 2.f / (1.f + exp2f((2.f * LOG2E) * x));
}
__device__ __forceinline__ floatx4 mfma16(short8 a, short8 b, floatx4 c) {
  return __builtin_amdgcn_mfma_f32_16x16x32_bf16(a, b, c, 0, 0, 0);
}
__device__ __forceinline__ floatx4 mfma8(long a, long b, floatx4 c) {
  return __builtin_amdgcn_mfma_f32_16x16x32_fp8_fp8(a, b, c, 0, 0, 0);
}

// ---------------------------------------------------------------------------
// K1: weight packing (layout unchanged from round 3/4).
// LSTM column order: global col n (0..511): wave w=n>>6, gate g=(n>>4)&3,
//   unit-in-wave v=n&15, hidden unit u=16w+v, source row = g*128+u.
// fp8 fragment-major: byte index = (((ks*8+w)*4+g)*64 + lane)*8 + j, where
//   k = ks*32 + (lane>>4)*8 + j, col-unit v = lane&15.
// ---------------------------------------------------------------------------
__global__ void pack_kernel(const float* __restrict__ whh0, const float* __restrict__ wih0,
                            const float* __restrict__ wih1, const float* __restrict__ whh1,
                            const float* __restrict__ cw1,
                            unsigned char* __restrict__ PB1,
                            unsigned char* __restrict__ PB2,
                            unsigned short* __restrict__ PBc) {
  int idx = blockIdx.x * 256 + threadIdx.x;
  if (idx < 81920) {  // PB1: 5ks*8w*4g*64*8 bytes
    int j = idx & 7, lane = (idx >> 3) & 63, rest = idx >> 9;
    int g = rest & 3, w = (rest >> 2) & 7, ks = rest >> 5;
    int k = ks * 32 + ((lane >> 4) << 3) + j;
    int u = w * 16 + (lane & 15), row = g * 128 + u;
    float val = 0.f;
    if (k < 128) val = whh0[row * 128 + k];
    else if (k < 138) val = wih0[row * 10 + (k - 128)];
    PB1[idx] = f2fp8(val);
  }
  if (idx < 131072) {  // PB2: 8ks*8w*4g*64*8 bytes
    int j = idx & 7, lane = (idx >> 3) & 63, rest = idx >> 9;
    int g = rest & 3, w = (rest >> 2) & 7, ks = rest >> 5;
    int k = ks * 32 + ((lane >> 4) << 3) + j;
    int u = w * 16 + (lane & 15), row = g * 128 + u;
    float val = (k < 128) ? wih1[row * 128 + k] : whh1[row * 128 + (k - 128)];
    PB2[idx] = f2fp8(val);
  }
  if (idx < 32768) {  // PBc: 8*8*64*8 bf16
    int j = idx & 7, lane = (idx >> 3) & 63, t2 = idx >> 9;
    int ti = t2 & 7, ks = t2 >> 3;
    int n = ti * 16 + (lane & 15);
    int k = ks * 32 + ((lane >> 4) << 3) + j;
    PBc[idx] = f2bf(cw1[n * 256 + k]);
  }
}

// ---------------------------------------------------------------------------
// K2: per-node softmax / argmax / entropy + GAT node features (unchanged)
// ---------------------------------------------------------------------------
__global__ void probs_kernel(const float* __restrict__ pred, const float* __restrict__ gW,
                             const float* __restrict__ gas, const float* __restrict__ gad,
                             float* __restrict__ out,
                             float* __restrict__ wprobs, float* __restrict__ wx,
                             float* __restrict__ was, float* __restrict__ wad,
                             int* __restrict__ wlab, float* __restrict__ wmp, int N) {
  __shared__ float sgW[400], sgas[40], sgad[40];
  int tid = threadIdx.x;
  for (int i = tid; i < 400; i += 256) sgW[i] = gW[i];
  if (tid < 40) { sgas[tid] = gas[tid]; sgad[tid] = gad[tid]; }
  __syncthreads();
  int node = blockIdx.x * 256 + tid;
  if (node >= N) return;
  const float* pr = pred + (size_t)node * NC;
  float p[NC];
#pragma unroll
  for (int c = 0; c < NC; c++) p[c] = pr[c];
  float pm = p[0]; int arg = 0;
#pragma unroll
  for (int c = 1; c < NC; c++) if (p[c] > pm) { pm = p[c]; arg = c; }
  float s = 0.f, prb[NC];
#pragma unroll
  for (int c = 0; c < NC; c++) { prb[c] = expf(p[c] - pm); s += prb[c]; }
  float inv = 1.f / s;
  float ent = 0.f;
#pragma unroll
  for (int c = 0; c < NC; c++) {
    prb[c] *= inv;
    wprobs[(size_t)node * NC + c] = prb[c];
    ent -= prb[c] * logf(prb[c] + 1e-8f);
  }
  out[node] = (float)arg;
  out[(size_t)3 * N + node] = inv;          // max prob = exp(0)/sum
  out[(size_t)7 * N + node] = ent * (1.f / 2.302585093f);
  wlab[node] = arg;
  wmp[node] = inv;
  float xv[40];
#pragma unroll
  for (int hc = 0; hc < 40; hc++) {
    float t = 0.f;
#pragma unroll
    for (int k = 0; k < NC; k++) t += prb[k] * sgW[k * 40 + hc];
    xv[hc] = t;
    wx[(size_t)node * 40 + hc] = t;
  }
#pragma unroll
  for (int h = 0; h < NHEADS; h++) {
    float as = 0.f, ad = 0.f;
#pragma unroll
    for (int c = 0; c < NC; c++) { as += xv[h * 10 + c] * sgas[h * 10 + c]; ad += xv[h * 10 + c] * sgad[h * 10 + c]; }
    was[(size_t)node * 4 + h] = as;
    wad[(size_t)node * 4 + h] = ad;
  }
}

// ---------------------------------------------------------------------------
// K3: confidence net (unchanged)
// ---------------------------------------------------------------------------
__global__ __launch_bounds__(256) void conf_kernel(const float* __restrict__ emb,
                                                   const unsigned short* __restrict__ PBc,
                                                   const float* __restrict__ cb1,
                                                   const float* __restrict__ cw2,
                                                   const float* __restrict__ cb2,
                                                   float* __restrict__ wec, int N) {
  __shared__ __align__(16) unsigned short astage[128 * 264];  // +8 pad: 2-way banks
  int tid = threadIdx.x;
  int base = blockIdx.x * 128;
  for (int i = tid * 4; i < 128 * 256; i += 1024) {
    int row = i >> 8, col = i & 255;
    float4 v = make_float4(0.f, 0.f, 0.f, 0.f);
    if (base + row < N) v = *(const float4*)(emb + (size_t)(base + row) * 256 + col);
    unsigned short* d = &astage[row * 264 + col];
    d[0] = f2bf(v.x); d[1] = f2bf(v.y); d[2] = f2bf(v.z); d[3] = f2bf(v.w);
  }
  __syncthreads();
  int wave = tid >> 6, lane = tid & 63, quad = lane >> 4, ln = lane & 15;
  float b1f[8], w2f[8];
#pragma unroll
  for (int t = 0; t < 8; t++) { b1f[t] = cb1[t * 16 + ln]; w2f[t] = cw2[t * 16 + ln]; }
  floatx4 acc[2][8];
#pragma unroll
  for (int mi = 0; mi < 2; mi++)
#pragma unroll
    for (int t = 0; t < 8; t++) acc[mi][t] = (floatx4){b1f[t], b1f[t], b1f[t], b1f[t]};
#pragma unroll
  for (int ks = 0; ks < 8; ks++) {
    short8 a0 = *(const short8*)&astage[(wave * 32 + ln) * 264 + ks * 32 + quad * 8];
    short8 a1 = *(const short8*)&astage[(wave * 32 + 16 + ln) * 264 + ks * 32 + quad * 8];
    const unsigned short* bp = PBc + (((size_t)(ks * 8) * 64 + lane) << 3);
#pragma unroll
    for (int t = 0; t < 8; t++) {
      short8 b = *(const short8*)(bp + (size_t)t * 512);
      acc[0][t] = mfma16(a0, b, acc[0][t]);
      acc[1][t] = mfma16(a1, b, acc[1][t]);
    }
  }
  float part[2][4];
#pragma unroll
  for (int mi = 0; mi < 2; mi++)
#pragma unroll
    for (int r = 0; r < 4; r++) {
      float t = 0.f;
#pragma unroll
      for (int ti = 0; ti < 8; ti++) t += fmaxf(acc[mi][ti][r], 0.f) * w2f[ti];
      part[mi][r] = t;
    }
#pragma unroll
  for (int off = 8; off >= 1; off >>= 1)
#pragma unroll
    for (int mi = 0; mi < 2; mi++)
#pragma unroll
      for (int r = 0; r < 4; r++) part[mi][r] += __shfl_xor(part[mi][r], off);
  if (ln == 0) {
    float b2 = cb2[0];
#pragma unroll
    for (int mi = 0; mi < 2; mi++)
#pragma unroll
      for (int r = 0; r < 4; r++) {
        int node = base + wave * 32 + mi * 16 + quad * 4 + r;
        if (node < N) wec[node] = sigf(part[mi][r] + b2);
      }
  }
}

// ---------------------------------------------------------------------------
// K4: fused 2-layer LSTM, fp8. 64 nodes/block, 512 threads (8 waves).
// Layer-1 weights (80 KB) staged in LDS; layer-2 weights (64 VGPR) in regs.
// Reg budget/lane: w2 64 + acc 64 + c/s 64 + temps ~30 = ~222 < 256 (no spill).
// h states double-buffered (4 x 64x136 fp8): 2 barriers per timestep.
// ---------------------------------------------------------------------------
#define HB 8704  // 64*136

__global__ __launch_bounds__(512, 2) void lstm_kernel(const float* __restrict__ pred,
                                                      const unsigned char* __restrict__ PB1,
                                                      const unsigned char* __restrict__ PB2,
                                                      const float* __restrict__ bih0,
                                                      const float* __restrict__ bhh0,
                                                      const float* __restrict__ bih1,
                                                      const float* __restrict__ bhh1,
                                                      float* __restrict__ wtc, int N) {
  __shared__ __align__(16) unsigned char sPB1[81920];  // layer-1 weights, whole block
  __shared__ __align__(16) unsigned char hb[4 * HB];   // [0]/[1]=h1 dbuf, [2]/[3]=h2 dbuf
  __shared__ __align__(16) unsigned char xbuf[64 * 40];
  __shared__ float varsum[64];
  int tid = threadIdx.x;
  int base = blockIdx.x * 64;
  // stage layer-1 weights (verbatim copy, fragment-major already)
  {
    const uint4* s4 = (const uint4*)PB1;
    uint4* d4 = (uint4*)sPB1;
    for (int i = tid; i < 81920 / 16; i += 512) d4[i] = s4[i];
  }
  for (int i = tid; i < HB; i += 512) { hb[i] = 0; hb[2 * HB + i] = 0; }
  for (int i = tid; i < 64 * 40; i += 512) {
    int nd = i / 40, o = i - nd * 40;
    float v = 0.f;
    if (o < 10 && base + nd < N) v = pred[(size_t)(base + nd) * NC + o];
    xbuf[i] = f2fp8(v);
  }
  if (tid < 64) varsum[tid] = 0.f;
  int wave = tid >> 6, lane = tid & 63, quad = lane >> 4, ln = lane & 15;
  float b0f[4], b1f[4];
#pragma unroll
  for (int g = 0; g < 4; g++) {
    int row = g * 128 + wave * 16 + ln;
    b0f[g] = bih0[row] + bhh0[row];
    b1f[g] = bih1[row] + bhh1[row];
  }
  // -------- layer-2 weight fragments in registers (loaded once) --------
  long w2r[8][4];
#pragma unroll
  for (int ks = 0; ks < 8; ks++)
#pragma unroll
    for (int g = 0; g < 4; g++)
      w2r[ks][g] = *(const long*)(PB2 + (size_t)(((ks * 8 + wave) * 4 + g) * 64 + lane) * 8);
  float c1[16], c2[16], s1[16], s2[16];
#pragma unroll
  for (int i = 0; i < 16; i++) { c1[i] = 0.f; c2[i] = 0.f; s1[i] = 0.f; s2[i] = 0.f; }
  const int hq = quad * 8;
  const int ucol = wave * 16 + ln;
  const int w1base = wave * 2048 + lane * 8;  // + ks*16384 + g*512 into sPB1
  int arow[4], wrow[4];
#pragma unroll
  for (int mt = 0; mt < 4; mt++) {
    arow[mt] = (mt * 16 + ln) * 136 + hq;          // A-frag read base (row, k-offset)
    wrow[mt] = (mt * 16 + quad * 4) * 136 + ucol;  // h write base (+ r*136)
  }
  __syncthreads();

// One timestep with compile-time buffer offsets.
// O1R: h1_prev read buf; O1W: h1_cur write buf; O2R: h2_prev; O2W: h2_cur.
#define LSTM_STEP(O1R, O1W, O2R, O2W)                                            \
  {                                                                              \
    floatx4 acc[4][4];                                                           \
    _Pragma("unroll") for (int mt = 0; mt < 4; mt++)                             \
        _Pragma("unroll") for (int g = 0; g < 4; g++)                            \
            acc[mt][g] = (floatx4){b0f[g], b0f[g], b0f[g], b0f[g]};              \
    _Pragma("unroll") for (int ks = 0; ks < 5; ks++) {                           \
      long a_[4];                                                                \
      if (ks < 4) {                                                              \
        _Pragma("unroll") for (int mt = 0; mt < 4; mt++)                         \
            a_[mt] = *(const long*)&hb[(O1R) + arow[mt] + ks * 32];              \
      } else {                                                                   \
        _Pragma("unroll") for (int mt = 0; mt < 4; mt++)                         \
            a_[mt] = *(const long*)&xbuf[(mt * 16 + ln) * 40 + hq];              \
      }                                                                          \
      _Pragma("unroll") for (int g = 0; g < 4; g++) {                            \
        long bw = *(const long*)&sPB1[w1base + ks * 16384 + g * 512];            \
        _Pragma("unroll") for (int mt = 0; mt < 4; mt++)                         \
            acc[mt][g] = mfma8(a_[mt], bw, acc[mt][g]);                          \
      }                                                                          \
    }                                                                            \
    _Pragma("unroll") for (int mt = 0; mt < 4; mt++)                             \
        _Pragma("unroll") for (int r = 0; r < 4; r++) {                          \
      int ci = mt * 4 + r;                                                       \
      float ig = sig2(acc[mt][0][r]);                                            \
      float fg = sig2(acc[mt][1][r]);                                            \
      float gg = tanh2(acc[mt][2][r]);                                           \
      float og = sig2(acc[mt][3][r]);                                            \
      float c = fg * c1[ci] + ig * gg;                                           \
      c1[ci] = c;                                                                \
      float h = og * tanh2(c);                                                   \
      hb[(O1W) + wrow[mt] + r * 136] = f2fp8(h);                                 \
    }                                                                            \
    __syncthreads();                                                             \
    _Pragma("unroll") for (int mt = 0; mt < 4; mt++)                             \
        _Pragma("unroll") for (int g = 0; g < 4; g++)                            \
            acc[mt][g] = (floatx4){b1f[g], b1f[g], b1f[g], b1f[g]};              \
    _Pragma("unroll") for (int ks = 0; ks < 8; ks++) {                           \
      long a_[4];                                                                \
      if (ks < 4) {                                                              \
        _Pragma("unroll") for (int mt = 0; mt < 4; mt++)                         \
            a_[mt] = *(const long*)&hb[(O1W) + arow[mt] + ks * 32];              \
      } else {                                                                   \
        _Pragma("unroll") for (int mt = 0; mt < 4; mt++)                         \
            a_[mt] = *(const long*)&hb[(O2R) + arow[mt] + (ks - 4) * 32];        \
      }                                                                          \
      _Pragma("unroll") for (int g = 0; g < 4; g++)                              \
          _Pragma("unroll") for (int mt = 0; mt < 4; mt++)                       \
              acc[mt][g] = mfma8(a_[mt], w2r[ks][g], acc[mt][g]);                \
    }                                                                            \
    _Pragma("unroll") for (int mt = 0; mt < 4; mt++)                             \
        _Pragma("unroll") for (int r = 0; r < 4; r++) {                          \
      int ci = mt * 4 + r;                                                       \
      float ig = sig2(acc[mt][0][r]);                                            \
      float fg = sig2(acc[mt][1][r]);                                            \
      float gg = tanh2(acc[mt][2][r]);                                           \
      float og = sig2(acc[mt][3][r]);                                            \
      float c = fg * c2[ci] + ig * gg;                                           \
      c2[ci] = c;                                                                \
      float h = og * tanh2(c);                                                   \
      s1[ci] += h;                                                               \
      s2[ci] += h * h;                                                           \
      hb[(O2W) + wrow[mt] + r * 136] = f2fp8(h);                                 \
    }                                                                            \
    __syncthreads();                                                             \
  }

  for (int tt = 0; tt < TSTEPS / 2; tt++) {
    LSTM_STEP(0, HB, 2 * HB, 3 * HB);
    LSTM_STEP(HB, 0, 3 * HB, 2 * HB);
  }
#undef LSTM_STEP

  // variance (ddof=1) per (node,unit), summed over 128 units via LDS atomics
#pragma unroll
  for (int mt = 0; mt < 4; mt++)
#pragma unroll
    for (int r = 0; r < 4; r++) {
      int ci = mt * 4 + r;
      float m = s1[ci] * (1.f / 12.f);
      float var = (s2[ci] - 12.f * m * m) * (1.f / 11.f);
      atomicAdd(&varsum[mt * 16 + quad * 4 + r], var);
    }
  __syncthreads();
  if (tid < 64 && base + tid < N)
    wtc[base + tid] = 1.f / (1.f + varsum[tid] * (1.f / 128.f));
}

// ---------------------------------------------------------------------------
// K5: degree histogram. indeg by dst (CSR rows), outdeg by src (agreement).
// ---------------------------------------------------------------------------
__global__ void hist_kernel(const int* __restrict__ ei, int* __restrict__ indeg,
                            int* __restrict__ outdeg, int E, int N) {
  int idx = blockIdx.x * 256 + threadIdx.x;
  if (idx >= E + N) return;
  int src, dst;
  if (idx < E) { src = ei[idx]; dst = ei[E + idx]; } else { src = dst = idx - E; }
  atomicAdd(&indeg[dst], 1);
  atomicAdd(&outdeg[src], 1);
}

// ---------------------------------------------------------------------------
// K6: 3-kernel exclusive scan of indeg -> rowptr (1024 elems/block)
// ---------------------------------------------------------------------------
__global__ void scan1_kernel(const int* __restrict__ indeg, int* __restrict__ rowptr,
                             int* __restrict__ partials, int N) {
  int t = threadIdx.x, b = blockIdx.x;
  int base = b * 1024 + t * 4;
  int v0 = 0, v1 = 0, v2 = 0, v3 = 0;
  if (base + 0 < N) v0 = indeg[base + 0];
  if (base + 1 < N) v1 = indeg[base + 1];
  if (base + 2 < N) v2 = indeg[base + 2];
  if (base + 3 < N) v3 = indeg[base + 3];
  int tsum = v0 + v1 + v2 + v3;
  int lane = t & 63, wv = t >> 6;
  int x = tsum;
#pragma unroll
  for (int d = 1; d < 64; d <<= 1) { int y = __shfl_up(x, d); if (lane >= d) x += y; }
  __shared__ int wsum[4];
  if (lane == 63) wsum[wv] = x;
  __syncthreads();
  int wo = 0;
  for (int i = 0; i < wv; i++) wo += wsum[i];
  int excl = wo + x - tsum;
  if (base + 0 < N) rowptr[base + 0] = excl;
  if (base + 1 < N) rowptr[base + 1] = excl + v0;
  if (base + 2 < N) rowptr[base + 2] = excl + v0 + v1;
  if (base + 3 < N) rowptr[base + 3] = excl + v0 + v1 + v2;
  if (t == 255) partials[b] = wo + x;  // block total
}

__global__ void scan2_kernel(int* __restrict__ partials, int nb) {
  int t = threadIdx.x;
  int lane = t & 63, wv = t >> 6;
  int v = (t < nb) ? partials[t] : 0;
  int x = v;
#pragma unroll
  for (int d = 1; d < 64; d <<= 1) { int y = __shfl_up(x, d); if (lane >= d) x += y; }
  __shared__ int wsum[4];
  if (lane == 63) wsum[wv] = x;
  __syncthreads();
  int wo = 0;
  for (int i = 0; i < wv; i++) wo += wsum[i];
  if (t < nb) partials[t] = wo + x - v;  // exclusive
}

__global__ void scan3_kernel(int* __restrict__ rowptr, int* __restrict__ cursor,
                             const int* __restrict__ partials, int N, int total) {
  int i = blockIdx.x * 256 + threadIdx.x;
  if (i < N) {
    int v = rowptr[i] + partials[i >> 10];
    rowptr[i] = v;
    cursor[i] = v;
  }
  if (i == 0) rowptr[N] = total;
}

// ---------------------------------------------------------------------------
// K7: scatter edges into CSR (1 int atomic per edge)
// ---------------------------------------------------------------------------
__global__ void scatter_kernel(const int* __restrict__ ei, int* __restrict__ cursor,
                               int* __restrict__ csr, int E, int N) {
  int idx = blockIdx.x * 256 + threadIdx.x;
  if (idx >= E + N) return;
  int src, dst;
  if (idx < E) { src = ei[idx]; dst = ei[E + idx]; } else { src = dst = idx - E; }
  int pos = atomicAdd(&cursor[dst], 1);
  csr[pos] = src;
}

// ---------------------------------------------------------------------------
// K8: gather + finalize. 4 threads per node (h = gid&3).
// ---------------------------------------------------------------------------
__global__ __launch_bounds__(256) void gather_final_kernel(
    const int* __restrict__ rowptr, const int* __restrict__ csr,
    const float* __restrict__ was, const float* __restrict__ wad,
    const float* __restrict__ wx, const int* __restrict__ wlab,
    const int* __restrict__ outdeg, const float* __restrict__ wprobs,
    const float* __restrict__ gb, const float* __restrict__ wmp,
    const float* __restrict__ wec, const float* __restrict__ wtc,
    float* __restrict__ out, int N) {
  int gid = blockIdx.x * 256 + threadIdx.x;
  int node = gid >> 2, h = gid & 3;
  if (node >= N) return;
  int beg = rowptr[node], end = rowptr[node + 1];
  float ad = wad[(size_t)node * 4 + h];
  int mylab = wlab[node];
  float mx = -1e30f;
  for (int e = beg; e < end; e++) {
    int s = csr[e];
    float v = was[(size_t)s * 4 + h] + ad;
    float lr = v >= 0.f ? v : 0.2f * v;
    mx = fmaxf(mx, lr);
  }
  float ssum = 0.f, cnt = 0.f;
  float accv[10];
#pragma unroll
  for (int c = 0; c < 10; c++) accv[c] = 0.f;
  for (int e = beg; e < end; e++) {
    int s = csr[e];
    float v = was[(size_t)s * 4 + h] + ad;
    float lr = v >= 0.f ? v : 0.2f * v;
    float ex = __expf(lr - mx);
    ssum += ex;
    const float* xr = wx + (size_t)s * 40 + h * 10;
#pragma unroll
    for (int c = 0; c < 10; c++) accv[c] += ex * xr[c];
    cnt += (wlab[s] == mylab) ? 1.f : 0.f;
  }
  float inv = 1.f / (ssum + 1e-16f);
  float gpart[10];
#pragma unroll
  for (int c = 0; c < 10; c++) gpart[c] = accv[c] * inv;
#pragma unroll
  for (int c = 0; c < 10; c++) {
    gpart[c] += __shfl_xor(gpart[c], 1);
    gpart[c] += __shfl_xor(gpart[c], 2);
  }
  if (h == 0) {
    float num = 0.f, np2 = 0.f, ng2 = 0.f;
#pragma unroll
    for (int c = 0; c < 10; c++) {
      float g = gpart[c] * 0.25f + gb[c];
      float p = wprobs[(size_t)node * 10 + c];
      num += p * g;
      np2 += p * p;
      ng2 += g * g;
    }
    float den = fmaxf(sqrtf(np2) * sqrtf(ng2), 1e-8f);
    float gc = (num / den + 1.f) * 0.5f;
    float mp = wmp[node], ec = wec[node], tc = wtc[node];
    float comb = 0.4f * mp + 0.2f * ec + 0.2f * tc + 0.2f * gc;
    float dgv = (float)outdeg[node];
    float navg = cnt / (dgv + 1e-8f);
    bool mask = (comb > 0.85f) && (navg >= 0.6f);
    out[(size_t)1 * N + node] = comb;
    out[(size_t)2 * N + node] = mask ? 1.f : 0.f;
    out[(size_t)4 * N + node] = ec;
    out[(size_t)5 * N + node] = tc;
    out[(size_t)6 * N + node] = gc;
  }
}

// ---------------------------------------------------------------------------
extern "C" void kernel_launch(void* const* d_in, const int* in_sizes, int n_in,
                              void* d_out, int out_size, void* d_ws, size_t ws_size,
                              hipStream_t stream) {
  const float* emb  = (const float*)d_in[0];
  const float* pred = (const float*)d_in[1];
  const int*   ei   = (const int*)d_in[3];
  const float* cw1  = (const float*)d_in[4];
  const float* cb1  = (const float*)d_in[5];
  const float* cw2  = (const float*)d_in[6];
  const float* cb2  = (const float*)d_in[7];
  const float* wih0 = (const float*)d_in[8];
  const float* whh0 = (const float*)d_in[9];
  const float* bih0 = (const float*)d_in[10];
  const float* bhh0 = (const float*)d_in[11];
  const float* wih1 = (const float*)d_in[12];
  const float* whh1 = (const float*)d_in[13];
  const float* bih1 = (const float*)d_in[14];
  const float* bhh1 = (const float*)d_in[15];
  const float* gW   = (const float*)d_in[16];
  const float* gas  = (const float*)d_in[17];
  const float* gad  = (const float*)d_in[18];
  const float* gb   = (const float*)d_in[19];

  const int N = in_sizes[0] / HIDN;
  const int E = in_sizes[3] / 2;
  float* out = (float*)d_out;
  float* ws = (float*)d_ws;
  const size_t sN = (size_t)N;

  float* wprobs = ws;                         // 10N
  float* wx     = ws + 10 * sN;               // 40N
  float* was    = ws + 50 * sN;               // 4N
  float* wad    = ws + 54 * sN;               // 4N
  int*   wlab   = (int*)(ws + 58 * sN);       // N
  float* wmp    = ws + 59 * sN;               // N
  float* wec    = ws + 60 * sN;               // N
  float* wtc    = ws + 61 * sN;               // N
  int* indeg    = (int*)(ws + 62 * sN);       // N   <- memset region start
  int* outdeg   = (int*)(ws + 63 * sN);       // N   <- memset region end (2N ints)
  int* rowptr   = (int*)(ws + 64 * sN);       // N+1 (+pad)
  int* cursor   = (int*)(ws + 65 * sN) + 64;  // N
  int* csr      = (int*)(ws + 66 * sN) + 128; // E+N
  int* partials = (int*)(ws + 67 * sN) + 128 + E;  // 256
  float* pbase  = ws + 67 * sN + 128 + E + 256;
  unsigned char* PB1 = (unsigned char*)pbase;                  // 81920 B
  unsigned char* PB2 = (unsigned char*)(pbase + 20480);        // 131072 B
  unsigned short* PBc = (unsigned short*)(pbase + 53248);      // 32768 ushort

  hipMemsetAsync(indeg, 0, 2 * sN * sizeof(int), stream);
  pack_kernel<<<512, 256, 0, stream>>>(whh0, wih0, wih1, whh1, cw1, PB1, PB2, PBc);
  probs_kernel<<<(N + 255) / 256, 256, 0, stream>>>(pred, gW, gas, gad, out, wprobs, wx,
                                                    was, wad, wlab, wmp, N);
  conf_kernel<<<(N + 127) / 128, 256, 0, stream>>>(emb, PBc, cb1, cw2, cb2, wec, N);
  lstm_kernel<<<(N + 63) / 64, 512, 0, stream>>>(pred, PB1, PB2, bih0, bhh0, bih1, bhh1,
                                                 wtc, N);
  int ne = E + N;
  hist_kernel<<<(ne + 255) / 256, 256, 0, stream>>>(ei, indeg, outdeg, E, N);
  int nb = (N + 1023) / 1024;
  scan1_kernel<<<nb, 256, 0, stream>>>(indeg, rowptr, partials, N);
  scan2_kernel<<<1, 256, 0, stream>>>(partials, nb);
  scan3_kernel<<<(N + 255) / 256, 256, 0, stream>>>(rowptr, cursor, partials, N, ne);
  scatter_kernel<<<(ne + 255) / 256, 256, 0, stream>>>(ei, cursor, csr, E, N);
  gather_final_kernel<<<(4 * N + 255) / 256, 256, 0, stream>>>(
      rowptr, csr, was, wad, wx, wlab, outdeg, wprobs, gb, wmp, wec, wtc, out, N);
}

// Round 6
// 2263.796 us; speedup vs baseline: 1.4231x; 1.4231x over previous
//
#include <hip/hip_runtime.h>
#include <hip/hip_bf16.h>

// ============================================================================
// PseudoLabelGenerator: round 6 — LSTM register-pressure fix:
//   M=32 nodes/block (acc 32, c/s 32), w1+w2 BOTH register-resident
//   (104 regs), total ~215 < 256 cap -> truly spill-free, no LDS w1 reads.
//   One barrier per timestep (12 total) via double-buffered h1/h2 segments.
//  K1 pack / K2 probs / K3 conf / K5-K7 CSR build / K8 gather: unchanged.
// ============================================================================

#define HIDN 256
#define NC 10
#define TSTEPS 12
#define NHEADS 4
#define LH 128

typedef __attribute__((ext_vector_type(8))) short short8;
typedef __attribute__((ext_vector_type(4))) float floatx4;

__device__ __forceinline__ unsigned short f2bf(float x) {
  unsigned u = __float_as_uint(x);
  u = u + 0x7FFFu + ((u >> 16) & 1u);   // round-to-nearest-even
  return (unsigned short)(u >> 16);
}
__device__ __forceinline__ unsigned char f2fp8(float x) {
  return (unsigned char)(__builtin_amdgcn_cvt_pk_fp8_f32(x, 0.f, 0, false) & 0xff);
}
__device__ __forceinline__ float sigf(float x) { return 1.0f / (1.0f + __expf(-x)); }
// exp2-based activations: branchless, saturate correctly at +-inf
#define LOG2E 1.44269504f
__device__ __forceinline__ float sig2(float x) {
  return 1.f / (1.f + exp2f(-LOG2E * x));
}
__device__ __forceinline__ float tanh2(float x) {
  return 1.f - 2.f / (1.f + exp2f((2.f * LOG2E) * x));
}
__device__ __forceinline__ floatx4 mfma16(short8 a, short8 b, floatx4 c) {
  return __builtin_amdgcn_mfma_f32_16x16x32_bf16(a, b, c, 0, 0, 0);
}
__device__ __forceinline__ floatx4 mfma8(long a, long b, floatx4 c) {
  return __builtin_amdgcn_mfma_f32_16x16x32_fp8_fp8(a, b, c, 0, 0, 0);
}

// ---------------------------------------------------------------------------
// K1: weight packing (layout unchanged).
// LSTM column order: global col n (0..511): wave w=n>>6, gate g=(n>>4)&3,
//   unit-in-wave v=n&15, hidden unit u=16w+v, source row = g*128+u.
// fp8 fragment-major: byte index = (((ks*8+w)*4+g)*64 + lane)*8 + j, where
//   k = ks*32 + (lane>>4)*8 + j, col-unit v = lane&15.
// ---------------------------------------------------------------------------
__global__ void pack_kernel(const float* __restrict__ whh0, const float* __restrict__ wih0,
                            const float* __restrict__ wih1, const float* __restrict__ whh1,
                            const float* __restrict__ cw1,
                            unsigned char* __restrict__ PB1,
                            unsigned char* __restrict__ PB2,
                            unsigned short* __restrict__ PBc) {
  int idx = blockIdx.x * 256 + threadIdx.x;
  if (idx < 81920) {  // PB1: 5ks*8w*4g*64*8 bytes
    int j = idx & 7, lane = (idx >> 3) & 63, rest = idx >> 9;
    int g = rest & 3, w = (rest >> 2) & 7, ks = rest >> 5;
    int k = ks * 32 + ((lane >> 4) << 3) + j;
    int u = w * 16 + (lane & 15), row = g * 128 + u;
    float val = 0.f;
    if (k < 128) val = whh0[row * 128 + k];
    else if (k < 138) val = wih0[row * 10 + (k - 128)];
    PB1[idx] = f2fp8(val);
  }
  if (idx < 131072) {  // PB2: 8ks*8w*4g*64*8 bytes
    int j = idx & 7, lane = (idx >> 3) & 63, rest = idx >> 9;
    int g = rest & 3, w = (rest >> 2) & 7, ks = rest >> 5;
    int k = ks * 32 + ((lane >> 4) << 3) + j;
    int u = w * 16 + (lane & 15), row = g * 128 + u;
    float val = (k < 128) ? wih1[row * 128 + k] : whh1[row * 128 + (k - 128)];
    PB2[idx] = f2fp8(val);
  }
  if (idx < 32768) {  // PBc: 8*8*64*8 bf16
    int j = idx & 7, lane = (idx >> 3) & 63, t2 = idx >> 9;
    int ti = t2 & 7, ks = t2 >> 3;
    int n = ti * 16 + (lane & 15);
    int k = ks * 32 + ((lane >> 4) << 3) + j;
    PBc[idx] = f2bf(cw1[n * 256 + k]);
  }
}

// ---------------------------------------------------------------------------
// K2: per-node softmax / argmax / entropy + GAT node features (unchanged)
// ---------------------------------------------------------------------------
__global__ void probs_kernel(const float* __restrict__ pred, const float* __restrict__ gW,
                             const float* __restrict__ gas, const float* __restrict__ gad,
                             float* __restrict__ out,
                             float* __restrict__ wprobs, float* __restrict__ wx,
                             float* __restrict__ was, float* __restrict__ wad,
                             int* __restrict__ wlab, float* __restrict__ wmp, int N) {
  __shared__ float sgW[400], sgas[40], sgad[40];
  int tid = threadIdx.x;
  for (int i = tid; i < 400; i += 256) sgW[i] = gW[i];
  if (tid < 40) { sgas[tid] = gas[tid]; sgad[tid] = gad[tid]; }
  __syncthreads();
  int node = blockIdx.x * 256 + tid;
  if (node >= N) return;
  const float* pr = pred + (size_t)node * NC;
  float p[NC];
#pragma unroll
  for (int c = 0; c < NC; c++) p[c] = pr[c];
  float pm = p[0]; int arg = 0;
#pragma unroll
  for (int c = 1; c < NC; c++) if (p[c] > pm) { pm = p[c]; arg = c; }
  float s = 0.f, prb[NC];
#pragma unroll
  for (int c = 0; c < NC; c++) { prb[c] = expf(p[c] - pm); s += prb[c]; }
  float inv = 1.f / s;
  float ent = 0.f;
#pragma unroll
  for (int c = 0; c < NC; c++) {
    prb[c] *= inv;
    wprobs[(size_t)node * NC + c] = prb[c];
    ent -= prb[c] * logf(prb[c] + 1e-8f);
  }
  out[node] = (float)arg;
  out[(size_t)3 * N + node] = inv;          // max prob = exp(0)/sum
  out[(size_t)7 * N + node] = ent * (1.f / 2.302585093f);
  wlab[node] = arg;
  wmp[node] = inv;
  float xv[40];
#pragma unroll
  for (int hc = 0; hc < 40; hc++) {
    float t = 0.f;
#pragma unroll
    for (int k = 0; k < NC; k++) t += prb[k] * sgW[k * 40 + hc];
    xv[hc] = t;
    wx[(size_t)node * 40 + hc] = t;
  }
#pragma unroll
  for (int h = 0; h < NHEADS; h++) {
    float as = 0.f, ad = 0.f;
#pragma unroll
    for (int c = 0; c < NC; c++) { as += xv[h * 10 + c] * sgas[h * 10 + c]; ad += xv[h * 10 + c] * sgad[h * 10 + c]; }
    was[(size_t)node * 4 + h] = as;
    wad[(size_t)node * 4 + h] = ad;
  }
}

// ---------------------------------------------------------------------------
// K3: confidence net (unchanged)
// ---------------------------------------------------------------------------
__global__ __launch_bounds__(256) void conf_kernel(const float* __restrict__ emb,
                                                   const unsigned short* __restrict__ PBc,
                                                   const float* __restrict__ cb1,
                                                   const float* __restrict__ cw2,
                                                   const float* __restrict__ cb2,
                                                   float* __restrict__ wec, int N) {
  __shared__ __align__(16) unsigned short astage[128 * 264];  // +8 pad: 2-way banks
  int tid = threadIdx.x;
  int base = blockIdx.x * 128;
  for (int i = tid * 4; i < 128 * 256; i += 1024) {
    int row = i >> 8, col = i & 255;
    float4 v = make_float4(0.f, 0.f, 0.f, 0.f);
    if (base + row < N) v = *(const float4*)(emb + (size_t)(base + row) * 256 + col);
    unsigned short* d = &astage[row * 264 + col];
    d[0] = f2bf(v.x); d[1] = f2bf(v.y); d[2] = f2bf(v.z); d[3] = f2bf(v.w);
  }
  __syncthreads();
  int wave = tid >> 6, lane = tid & 63, quad = lane >> 4, ln = lane & 15;
  float b1f[8], w2f[8];
#pragma unroll
  for (int t = 0; t < 8; t++) { b1f[t] = cb1[t * 16 + ln]; w2f[t] = cw2[t * 16 + ln]; }
  floatx4 acc[2][8];
#pragma unroll
  for (int mi = 0; mi < 2; mi++)
#pragma unroll
    for (int t = 0; t < 8; t++) acc[mi][t] = (floatx4){b1f[t], b1f[t], b1f[t], b1f[t]};
#pragma unroll
  for (int ks = 0; ks < 8; ks++) {
    short8 a0 = *(const short8*)&astage[(wave * 32 + ln) * 264 + ks * 32 + quad * 8];
    short8 a1 = *(const short8*)&astage[(wave * 32 + 16 + ln) * 264 + ks * 32 + quad * 8];
    const unsigned short* bp = PBc + (((size_t)(ks * 8) * 64 + lane) << 3);
#pragma unroll
    for (int t = 0; t < 8; t++) {
      short8 b = *(const short8*)(bp + (size_t)t * 512);
      acc[0][t] = mfma16(a0, b, acc[0][t]);
      acc[1][t] = mfma16(a1, b, acc[1][t]);
    }
  }
  float part[2][4];
#pragma unroll
  for (int mi = 0; mi < 2; mi++)
#pragma unroll
    for (int r = 0; r < 4; r++) {
      float t = 0.f;
#pragma unroll
      for (int ti = 0; ti < 8; ti++) t += fmaxf(acc[mi][ti][r], 0.f) * w2f[ti];
      part[mi][r] = t;
    }
#pragma unroll
  for (int off = 8; off >= 1; off >>= 1)
#pragma unroll
    for (int mi = 0; mi < 2; mi++)
#pragma unroll
      for (int r = 0; r < 4; r++) part[mi][r] += __shfl_xor(part[mi][r], off);
  if (ln == 0) {
    float b2 = cb2[0];
#pragma unroll
    for (int mi = 0; mi < 2; mi++)
#pragma unroll
      for (int r = 0; r < 4; r++) {
        int node = base + wave * 32 + mi * 16 + quad * 4 + r;
        if (node < N) wec[node] = sigf(part[mi][r] + b2);
      }
  }
}

// ---------------------------------------------------------------------------
// K4: fused 2-layer LSTM, fp8. 32 nodes/block, 512 threads (8 waves).
// Wave w owns units [16w,16w+16) x 4 gates. All weights register-resident:
// w1r 40 + w2r 64 + acc 32 + c/s 32 + temps ~45 = ~215 regs < 256 (no spill).
// One barrier per timestep: segment = [phase2(t); phase1(t+1)] on
// double-buffered h1/h2 (no intra-segment hazards).
// ---------------------------------------------------------------------------
#define HB2 4352  // 32*136

__global__ __launch_bounds__(512, 2) void lstm_kernel(const float* __restrict__ pred,
                                                      const unsigned char* __restrict__ PB1,
                                                      const unsigned char* __restrict__ PB2,
                                                      const float* __restrict__ bih0,
                                                      const float* __restrict__ bhh0,
                                                      const float* __restrict__ bih1,
                                                      const float* __restrict__ bhh1,
                                                      float* __restrict__ wtc, int N) {
  __shared__ __align__(16) unsigned char hb[4 * HB2];  // h1: [0],[HB2]; h2: [2HB2],[3HB2]
  __shared__ __align__(16) unsigned char xbuf[32 * 40];
  __shared__ float varsum[32];
  int tid = threadIdx.x;
  int base = blockIdx.x * 32;
  for (int i = tid; i < HB2; i += 512) hb[3 * HB2 + i] = 0;  // h2[-1] = 0
  for (int i = tid; i < 32 * 40; i += 512) {
    int nd = i / 40, o = i - nd * 40;
    float v = 0.f;
    if (o < 10 && base + nd < N) v = pred[(size_t)(base + nd) * NC + o];
    xbuf[i] = f2fp8(v);
  }
  if (tid < 32) varsum[tid] = 0.f;
  int wave = tid >> 6, lane = tid & 63, quad = lane >> 4, ln = lane & 15;
  float b0f[4], b1f[4];
#pragma unroll
  for (int g = 0; g < 4; g++) {
    int row = g * 128 + wave * 16 + ln;
    b0f[g] = bih0[row] + bhh0[row];
    b1f[g] = bih1[row] + bhh1[row];
  }
  // -------- all weight fragments in registers (loaded once) --------
  long w1r[5][4], w2r[8][4];
#pragma unroll
  for (int ks = 0; ks < 5; ks++)
#pragma unroll
    for (int g = 0; g < 4; g++)
      w1r[ks][g] = *(const long*)(PB1 + (size_t)(((ks * 8 + wave) * 4 + g) * 64 + lane) * 8);
#pragma unroll
  for (int ks = 0; ks < 8; ks++)
#pragma unroll
    for (int g = 0; g < 4; g++)
      w2r[ks][g] = *(const long*)(PB2 + (size_t)(((ks * 8 + wave) * 4 + g) * 64 + lane) * 8);
  float c1[8], c2[8], s1[8], s2[8];
#pragma unroll
  for (int i = 0; i < 8; i++) { c1[i] = 0.f; c2[i] = 0.f; s1[i] = 0.f; s2[i] = 0.f; }
  const int hq = quad * 8;
  const int ucol = wave * 16 + ln;
  int arow[2], wrow[2];
#pragma unroll
  for (int mt = 0; mt < 2; mt++) {
    arow[mt] = (mt * 16 + ln) * 136 + hq;          // A-frag read base
    wrow[mt] = (mt * 16 + quad * 4) * 136 + ucol;  // h write base (+ r*136)
  }
  __syncthreads();  // xbuf ready
  long xa[2];
  xa[0] = *(const long*)&xbuf[ln * 40 + hq];
  xa[1] = *(const long*)&xbuf[(16 + ln) * 40 + hq];

  // ----- prime: phase1(t=0), h1 state = 0 -> only x term + bias -----
  {
    floatx4 acc[2][4];
#pragma unroll
    for (int mt = 0; mt < 2; mt++)
#pragma unroll
      for (int g = 0; g < 4; g++) acc[mt][g] = (floatx4){b0f[g], b0f[g], b0f[g], b0f[g]};
#pragma unroll
    for (int g = 0; g < 4; g++)
#pragma unroll
      for (int mt = 0; mt < 2; mt++) acc[mt][g] = mfma8(xa[mt], w1r[4][g], acc[mt][g]);
#pragma unroll
    for (int mt = 0; mt < 2; mt++)
#pragma unroll
      for (int r = 0; r < 4; r++) {
        int ci = mt * 4 + r;
        float ig = sig2(acc[mt][0][r]);
        float gg = tanh2(acc[mt][2][r]);
        float og = sig2(acc[mt][3][r]);
        float c = ig * gg;  // f*c_prev = 0
        c1[ci] = c;
        hb[0 + wrow[mt] + r * 136] = f2fp8(og * tanh2(c));
      }
  }

// Segment: barrier; phase2(t) [O1R=h1[t], O2R=h2[t-1] -> O2W=h2[t]];
//          then (unless last) phase1(t+1) [O1R + x -> O1W=h1[t+1]].
#define LSTM_SEG(O1R, O1W, O2R, O2W, lastseg)                                    \
  {                                                                              \
    __syncthreads();                                                             \
    floatx4 acc[2][4];                                                           \
    _Pragma("unroll") for (int mt = 0; mt < 2; mt++)                             \
        _Pragma("unroll") for (int g = 0; g < 4; g++)                            \
            acc[mt][g] = (floatx4){b1f[g], b1f[g], b1f[g], b1f[g]};              \
    _Pragma("unroll") for (int ks = 0; ks < 8; ks++) {                           \
      long a_[2];                                                                \
      if (ks < 4) {                                                              \
        _Pragma("unroll") for (int mt = 0; mt < 2; mt++)                         \
            a_[mt] = *(const long*)&hb[(O1R) + arow[mt] + ks * 32];              \
      } else {                                                                   \
        _Pragma("unroll") for (int mt = 0; mt < 2; mt++)                         \
            a_[mt] = *(const long*)&hb[(O2R) + arow[mt] + (ks - 4) * 32];        \
      }                                                                          \
      _Pragma("unroll") for (int g = 0; g < 4; g++)                              \
          _Pragma("unroll") for (int mt = 0; mt < 2; mt++)                       \
              acc[mt][g] = mfma8(a_[mt], w2r[ks][g], acc[mt][g]);                \
    }                                                                            \
    _Pragma("unroll") for (int mt = 0; mt < 2; mt++)                             \
        _Pragma("unroll") for (int r = 0; r < 4; r++) {                          \
      int ci = mt * 4 + r;                                                       \
      float ig = sig2(acc[mt][0][r]);                                            \
      float fg = sig2(acc[mt][1][r]);                                            \
      float gg = tanh2(acc[mt][2][r]);                                           \
      float og = sig2(acc[mt][3][r]);                                            \
      float c = fg * c2[ci] + ig * gg;                                           \
      c2[ci] = c;                                                                \
      float h = og * tanh2(c);                                                   \
      s1[ci] += h;                                                               \
      s2[ci] += h * h;                                                           \
      hb[(O2W) + wrow[mt] + r * 136] = f2fp8(h);                                 \
    }                                                                            \
    if (!(lastseg)) {                                                            \
      _Pragma("unroll") for (int mt = 0; mt < 2; mt++)                           \
          _Pragma("unroll") for (int g = 0; g < 4; g++)                          \
              acc[mt][g] = (floatx4){b0f[g], b0f[g], b0f[g], b0f[g]};            \
      _Pragma("unroll") for (int ks = 0; ks < 5; ks++) {                         \
        long a_[2];                                                              \
        if (ks < 4) {                                                            \
          _Pragma("unroll") for (int mt = 0; mt < 2; mt++)                       \
              a_[mt] = *(const long*)&hb[(O1R) + arow[mt] + ks * 32];            \
        } else {                                                                 \
          a_[0] = xa[0]; a_[1] = xa[1];                                          \
        }                                                                        \
        _Pragma("unroll") for (int g = 0; g < 4; g++)                            \
            _Pragma("unroll") for (int mt = 0; mt < 2; mt++)                     \
                acc[mt][g] = mfma8(a_[mt], w1r[ks][g], acc[mt][g]);              \
      }                                                                          \
      _Pragma("unroll") for (int mt = 0; mt < 2; mt++)                           \
          _Pragma("unroll") for (int r = 0; r < 4; r++) {                        \
        int ci = mt * 4 + r;                                                     \
        float ig = sig2(acc[mt][0][r]);                                          \
        float fg = sig2(acc[mt][1][r]);                                          \
        float gg = tanh2(acc[mt][2][r]);                                         \
        float og = sig2(acc[mt][3][r]);                                          \
        float c = fg * c1[ci] + ig * gg;                                         \
        c1[ci] = c;                                                              \
        hb[(O1W) + wrow[mt] + r * 136] = f2fp8(og * tanh2(c));                   \
      }                                                                          \
    }                                                                            \
  }

  for (int tt = 0; tt < TSTEPS / 2; tt++) {
    // even t: h1[t] in buf0, writes h1[t+1]->buf1; h2[t-1] in buf1, h2[t]->buf0
    LSTM_SEG(0, HB2, 3 * HB2, 2 * HB2, false);
    // odd t: h1 in buf1 -> buf0; h2 prev buf0 -> buf1
    LSTM_SEG(HB2, 0, 2 * HB2, 3 * HB2, tt == TSTEPS / 2 - 1);
  }
#undef LSTM_SEG

  // variance (ddof=1) per (node,unit), summed over 128 units via LDS atomics
#pragma unroll
  for (int mt = 0; mt < 2; mt++)
#pragma unroll
    for (int r = 0; r < 4; r++) {
      int ci = mt * 4 + r;
      float m = s1[ci] * (1.f / 12.f);
      float var = (s2[ci] - 12.f * m * m) * (1.f / 11.f);
      atomicAdd(&varsum[mt * 16 + quad * 4 + r], var);
    }
  __syncthreads();
  if (tid < 32 && base + tid < N)
    wtc[base + tid] = 1.f / (1.f + varsum[tid] * (1.f / 128.f));
}

// ---------------------------------------------------------------------------
// K5: degree histogram. indeg by dst (CSR rows), outdeg by src (agreement).
// ---------------------------------------------------------------------------
__global__ void hist_kernel(const int* __restrict__ ei, int* __restrict__ indeg,
                            int* __restrict__ outdeg, int E, int N) {
  int idx = blockIdx.x * 256 + threadIdx.x;
  if (idx >= E + N) return;
  int src, dst;
  if (idx < E) { src = ei[idx]; dst = ei[E + idx]; } else { src = dst = idx - E; }
  atomicAdd(&indeg[dst], 1);
  atomicAdd(&outdeg[src], 1);
}

// ---------------------------------------------------------------------------
// K6: 3-kernel exclusive scan of indeg -> rowptr (1024 elems/block)
// ---------------------------------------------------------------------------
__global__ void scan1_kernel(const int* __restrict__ indeg, int* __restrict__ rowptr,
                             int* __restrict__ partials, int N) {
  int t = threadIdx.x, b = blockIdx.x;
  int base = b * 1024 + t * 4;
  int v0 = 0, v1 = 0, v2 = 0, v3 = 0;
  if (base + 0 < N) v0 = indeg[base + 0];
  if (base + 1 < N) v1 = indeg[base + 1];
  if (base + 2 < N) v2 = indeg[base + 2];
  if (base + 3 < N) v3 = indeg[base + 3];
  int tsum = v0 + v1 + v2 + v3;
  int lane = t & 63, wv = t >> 6;
  int x = tsum;
#pragma unroll
  for (int d = 1; d < 64; d <<= 1) { int y = __shfl_up(x, d); if (lane >= d) x += y; }
  __shared__ int wsum[4];
  if (lane == 63) wsum[wv] = x;
  __syncthreads();
  int wo = 0;
  for (int i = 0; i < wv; i++) wo += wsum[i];
  int excl = wo + x - tsum;
  if (base + 0 < N) rowptr[base + 0] = excl;
  if (base + 1 < N) rowptr[base + 1] = excl + v0;
  if (base + 2 < N) rowptr[base + 2] = excl + v0 + v1;
  if (base + 3 < N) rowptr[base + 3] = excl + v0 + v1 + v2;
  if (t == 255) partials[b] = wo + x;  // block total
}

__global__ void scan2_kernel(int* __restrict__ partials, int nb) {
  int t = threadIdx.x;
  int lane = t & 63, wv = t >> 6;
  int v = (t < nb) ? partials[t] : 0;
  int x = v;
#pragma unroll
  for (int d = 1; d < 64; d <<= 1) { int y = __shfl_up(x, d); if (lane >= d) x += y; }
  __shared__ int wsum[4];
  if (lane == 63) wsum[wv] = x;
  __syncthreads();
  int wo = 0;
  for (int i = 0; i < wv; i++) wo += wsum[i];
  if (t < nb) partials[t] = wo + x - v;  // exclusive
}

__global__ void scan3_kernel(int* __restrict__ rowptr, int* __restrict__ cursor,
                             const int* __restrict__ partials, int N, int total) {
  int i = blockIdx.x * 256 + threadIdx.x;
  if (i < N) {
    int v = rowptr[i] + partials[i >> 10];
    rowptr[i] = v;
    cursor[i] = v;
  }
  if (i == 0) rowptr[N] = total;
}

// ---------------------------------------------------------------------------
// K7: scatter edges into CSR (1 int atomic per edge)
// ---------------------------------------------------------------------------
__global__ void scatter_kernel(const int* __restrict__ ei, int* __restrict__ cursor,
                               int* __restrict__ csr, int E, int N) {
  int idx = blockIdx.x * 256 + threadIdx.x;
  if (idx >= E + N) return;
  int src, dst;
  if (idx < E) { src = ei[idx]; dst = ei[E + idx]; } else { src = dst = idx - E; }
  int pos = atomicAdd(&cursor[dst], 1);
  csr[pos] = src;
}

// ---------------------------------------------------------------------------
// K8: gather + finalize. 4 threads per node (h = gid&3).
// ---------------------------------------------------------------------------
__global__ __launch_bounds__(256) void gather_final_kernel(
    const int* __restrict__ rowptr, const int* __restrict__ csr,
    const float* __restrict__ was, const float* __restrict__ wad,
    const float* __restrict__ wx, const int* __restrict__ wlab,
    const int* __restrict__ outdeg, const float* __restrict__ wprobs,
    const float* __restrict__ gb, const float* __restrict__ wmp,
    const float* __restrict__ wec, const float* __restrict__ wtc,
    float* __restrict__ out, int N) {
  int gid = blockIdx.x * 256 + threadIdx.x;
  int node = gid >> 2, h = gid & 3;
  if (node >= N) return;
  int beg = rowptr[node], end = rowptr[node + 1];
  float ad = wad[(size_t)node * 4 + h];
  int mylab = wlab[node];
  float mx = -1e30f;
  for (int e = beg; e < end; e++) {
    int s = csr[e];
    float v = was[(size_t)s * 4 + h] + ad;
    float lr = v >= 0.f ? v : 0.2f * v;
    mx = fmaxf(mx, lr);
  }
  float ssum = 0.f, cnt = 0.f;
  float accv[10];
#pragma unroll
  for (int c = 0; c < 10; c++) accv[c] = 0.f;
  for (int e = beg; e < end; e++) {
    int s = csr[e];
    float v = was[(size_t)s * 4 + h] + ad;
    float lr = v >= 0.f ? v : 0.2f * v;
    float ex = __expf(lr - mx);
    ssum += ex;
    const float* xr = wx + (size_t)s * 40 + h * 10;
#pragma unroll
    for (int c = 0; c < 10; c++) accv[c] += ex * xr[c];
    cnt += (wlab[s] == mylab) ? 1.f : 0.f;
  }
  float inv = 1.f / (ssum + 1e-16f);
  float gpart[10];
#pragma unroll
  for (int c = 0; c < 10; c++) gpart[c] = accv[c] * inv;
#pragma unroll
  for (int c = 0; c < 10; c++) {
    gpart[c] += __shfl_xor(gpart[c], 1);
    gpart[c] += __shfl_xor(gpart[c], 2);
  }
  if (h == 0) {
    float num = 0.f, np2 = 0.f, ng2 = 0.f;
#pragma unroll
    for (int c = 0; c < 10; c++) {
      float g = gpart[c] * 0.25f + gb[c];
      float p = wprobs[(size_t)node * 10 + c];
      num += p * g;
      np2 += p * p;
      ng2 += g * g;
    }
    float den = fmaxf(sqrtf(np2) * sqrtf(ng2), 1e-8f);
    float gc = (num / den + 1.f) * 0.5f;
    float mp = wmp[node], ec = wec[node], tc = wtc[node];
    float comb = 0.4f * mp + 0.2f * ec + 0.2f * tc + 0.2f * gc;
    float dgv = (float)outdeg[node];
    float navg = cnt / (dgv + 1e-8f);
    bool mask = (comb > 0.85f) && (navg >= 0.6f);
    out[(size_t)1 * N + node] = comb;
    out[(size_t)2 * N + node] = mask ? 1.f : 0.f;
    out[(size_t)4 * N + node] = ec;
    out[(size_t)5 * N + node] = tc;
    out[(size_t)6 * N + node] = gc;
  }
}

// ---------------------------------------------------------------------------
extern "C" void kernel_launch(void* const* d_in, const int* in_sizes, int n_in,
                              void* d_out, int out_size, void* d_ws, size_t ws_size,
                              hipStream_t stream) {
  const float* emb  = (const float*)d_in[0];
  const float* pred = (const float*)d_in[1];
  const int*   ei   = (const int*)d_in[3];
  const float* cw1  = (const float*)d_in[4];
  const float* cb1  = (const float*)d_in[5];
  const float* cw2  = (const float*)d_in[6];
  const float* cb2  = (const float*)d_in[7];
  const float* wih0 = (const float*)d_in[8];
  const float* whh0 = (const float*)d_in[9];
  const float* bih0 = (const float*)d_in[10];
  const float* bhh0 = (const float*)d_in[11];
  const float* wih1 = (const float*)d_in[12];
  const float* whh1 = (const float*)d_in[13];
  const float* bih1 = (const float*)d_in[14];
  const float* bhh1 = (const float*)d_in[15];
  const float* gW   = (const float*)d_in[16];
  const float* gas  = (const float*)d_in[17];
  const float* gad  = (const float*)d_in[18];
  const float* gb   = (const float*)d_in[19];

  const int N = in_sizes[0] / HIDN;
  const int E = in_sizes[3] / 2;
  float* out = (float*)d_out;
  float* ws = (float*)d_ws;
  const size_t sN = (size_t)N;

  float* wprobs = ws;                         // 10N
  float* wx     = ws + 10 * sN;               // 40N
  float* was    = ws + 50 * sN;               // 4N
  float* wad    = ws + 54 * sN;               // 4N
  int*   wlab   = (int*)(ws + 58 * sN);       // N
  float* wmp    = ws + 59 * sN;               // N
  float* wec    = ws + 60 * sN;               // N
  float* wtc    = ws + 61 * sN;               // N
  int* indeg    = (int*)(ws + 62 * sN);       // N   <- memset region start
  int* outdeg   = (int*)(ws + 63 * sN);       // N   <- memset region end (2N ints)
  int* rowptr   = (int*)(ws + 64 * sN);       // N+1 (+pad)
  int* cursor   = (int*)(ws + 65 * sN) + 64;  // N
  int* csr      = (int*)(ws + 66 * sN) + 128; // E+N
  int* partials = (int*)(ws + 67 * sN) + 128 + E;  // 256
  float* pbase  = ws + 67 * sN + 128 + E + 256;
  unsigned char* PB1 = (unsigned char*)pbase;                  // 81920 B
  unsigned char* PB2 = (unsigned char*)(pbase + 20480);        // 131072 B
  unsigned short* PBc = (unsigned short*)(pbase + 53248);      // 32768 ushort

  hipMemsetAsync(indeg, 0, 2 * sN * sizeof(int), stream);
  pack_kernel<<<512, 256, 0, stream>>>(whh0, wih0, wih1, whh1, cw1, PB1, PB2, PBc);
  probs_kernel<<<(N + 255) / 256, 256, 0, stream>>>(pred, gW, gas, gad, out, wprobs, wx,
                                                    was, wad, wlab, wmp, N);
  conf_kernel<<<(N + 127) / 128, 256, 0, stream>>>(emb, PBc, cb1, cw2, cb2, wec, N);
  lstm_kernel<<<(N + 31) / 32, 512, 0, stream>>>(pred, PB1, PB2, bih0, bhh0, bih1, bhh1,
                                                 wtc, N);
  int ne = E + N;
  hist_kernel<<<(ne + 255) / 256, 256, 0, stream>>>(ei, indeg, outdeg, E, N);
  int nb = (N + 1023) / 1024;
  scan1_kernel<<<nb, 256, 0, stream>>>(indeg, rowptr, partials, N);
  scan2_kernel<<<1, 256, 0, stream>>>(partials, nb);
  scan3_kernel<<<(N + 255) / 256, 256, 0, stream>>>(rowptr, cursor, partials, N, ne);
  scatter_kernel<<<(ne + 255) / 256, 256, 0, stream>>>(ei, cursor, csr, E, N);
  gather_final_kernel<<<(4 * N + 255) / 256, 256, 0, stream>>>(
      rowptr, csr, was, wad, wx, wlab, outdeg, wprobs, gb, wmp, wec, wtc, out, N);
}